// Round 4
// baseline (196.139 us; speedup 1.0000x reference)
//
#include <hip/hip_runtime.h>

#define NN 50000
#define KE 32
#define PAD_N 50048     // padded rows per V plane

using f32x4  = __attribute__((ext_vector_type(4))) float;
using bf16x8 = __attribute__((ext_vector_type(8))) short;

__device__ __forceinline__ ushort f2bf(float f) {
    union { float f; unsigned u; } c; c.f = f;
    unsigned u = c.u;
    u += 0x7fffu + ((u >> 16) & 1u);        // round-to-nearest-even
    return (ushort)(u >> 16);
}
__device__ __forceinline__ ushort f2h(float f) {
    union { _Float16 h; ushort u; } c; c.h = (_Float16)f; return c.u;
}
__device__ __forceinline__ float h2f(ushort u) {
    union { ushort u; _Float16 h; } c; c.u = u; return (float)c.h;
}

// Kernel A (blocks 0-1): fold attn_vec through W_q/W_k into bf16 Ub[16][128]
// (cols 0-3 = u_h, 4-7 = v_h, rows 8-15 zeroed for MFMA B-operand).
// Blocks 2..129: cast W_v into Bt[n][k] = bf16(W_v[k][n]).
__global__ __launch_bounds__(256) void prep_kernel(const float* __restrict__ Wq,
        const float* __restrict__ Wk, const float* __restrict__ av,
        const float* __restrict__ Wv, ushort* __restrict__ Ub,
        ushort* __restrict__ Bt) {
    const int g = blockIdx.x * 256 + threadIdx.x;
    if (blockIdx.x < 2) {
        const int h = g >> 7, i = g & 127;
        float su = 0.f, sv = 0.f;
#pragma unroll
        for (int d = 0; d < 32; ++d) {
            su += Wq[i * 128 + h * 32 + d] * av[h * 64 + d];
            sv += Wk[i * 128 + h * 32 + d] * av[h * 64 + 32 + d];
        }
        Ub[h * 128 + i] = f2bf(su);
        Ub[(4 + h) * 128 + i] = f2bf(sv);
        Ub[1024 + g * 2] = 0;               // zero rows 8..15
        Ub[1024 + g * 2 + 1] = 0;
    } else {
        const int idx = g - 512;            // coalesced read of Wv
        const int k = idx >> 7, n = idx & 127;
        Bt[n * 256 + k] = f2bf(Wv[idx]);
    }
}

// Kernel B: V = concat(x, emb) @ W_v via bf16 MFMA + fused sq/sk scores.
// Bt fragments preloaded to registers before the barrier; epilogue writes V
// into 4 column-sliced planes Vp[head][node][32] (bf16) for L2 locality.
__global__ __launch_bounds__(256) void vproj_mfma(const float* __restrict__ x,
        const float* __restrict__ emb, const ushort* __restrict__ Bt,
        const ushort* __restrict__ Ub, float* __restrict__ sq,
        float* __restrict__ sk, ushort* __restrict__ Vp) {
    __shared__ short As[64 * 264];
    const int t = threadIdx.x;
    const int rbase = blockIdx.x * 64;
    const int wv = t >> 6;
    const int lane = t & 63;
    const int lo = lane & 15;
    const int quad = lane >> 4;
    const int c0 = wv * 32;

    // ---- stage A: 64 rows x 256 k, fp32 -> bf16 ----
#pragma unroll
    for (int it = 0; it < 16; ++it) {
        const int li = it * 256 + t;
        const int row = li >> 6;
        const int c4 = li & 63;
        int rg = rbase + row; if (rg >= NN) rg = NN - 1;
        const float* sp = (c4 < 32) ? (x + (long)rg * 128 + c4 * 4)
                                    : (emb + (long)rg * 128 + (c4 - 32) * 4);
        float4 a = *(const float4*)sp;
        ushort4 b = make_ushort4(f2bf(a.x), f2bf(a.y), f2bf(a.z), f2bf(a.w));
        *(ushort4*)&As[row * 264 + c4 * 4] = b;
    }
    // ---- preload all Bt fragments (latency overlaps the barrier) ----
    bf16x8 bt0[8], bt1[8];
#pragma unroll
    for (int ks = 0; ks < 8; ++ks) {
        const int kb = ks * 32 + quad * 8;
        bt0[ks] = *(const bf16x8*)(Bt + (c0 + lo) * 256 + kb);
        bt1[ks] = *(const bf16x8*)(Bt + (c0 + 16 + lo) * 256 + kb);
    }
    __syncthreads();

    f32x4 acc[4][2] = {};
#pragma unroll
    for (int ks = 0; ks < 8; ++ks) {
        const int kb = ks * 32 + quad * 8;
#pragma unroll
        for (int rt = 0; rt < 4; ++rt) {
            bf16x8 af = *(const bf16x8*)&As[(rt * 16 + lo) * 264 + kb];
            acc[rt][0] = __builtin_amdgcn_mfma_f32_16x16x32_bf16(af, bt0[ks], acc[rt][0], 0, 0, 0);
            acc[rt][1] = __builtin_amdgcn_mfma_f32_16x16x32_bf16(af, bt1[ks], acc[rt][1], 0, 0, 0);
        }
    }

    // ---- scores: wave wv handles rows wv*16..+15 (emb half of As) ----
    f32x4 sacc = {};
#pragma unroll
    for (int ks = 0; ks < 4; ++ks) {
        const int kk = ks * 32 + quad * 8;
        bf16x8 saf = *(const bf16x8*)&As[(wv * 16 + lo) * 264 + 128 + kk];
        bf16x8 sbf = *(const bf16x8*)(Ub + lo * 128 + kk);
        sacc = __builtin_amdgcn_mfma_f32_16x16x32_bf16(saf, sbf, sacc, 0, 0, 0);
    }
    if (lo < 8) {
#pragma unroll
        for (int r = 0; r < 4; ++r) {
            const int row = rbase + wv * 16 + quad * 4 + r;
            if (row < NN) {
                if (lo < 4) sq[(long)row * 4 + lo] = sacc[r];
                else        sk[(long)row * 4 + lo - 4] = sacc[r];
            }
        }
    }

    // ---- epilogue: regs -> LDS (stride 132) -> sliced planes ----
    __syncthreads();
#pragma unroll
    for (int rt = 0; rt < 4; ++rt)
#pragma unroll
        for (int ct = 0; ct < 2; ++ct)
#pragma unroll
            for (int r = 0; r < 4; ++r)
                As[(rt * 16 + quad * 4 + r) * 132 + c0 + ct * 16 + lo] =
                    (short)f2bf(acc[rt][ct][r]);
    __syncthreads();
#pragma unroll
    for (int i = 0; i < 4; ++i) {
        const int idx = i * 256 + t;
        const int row = idx >> 4;
        const int seg = idx & 15;           // cols seg*8 .. seg*8+7
        const int grow = rbase + row;
        const int plane = seg >> 2;         // head
        const int pc = (seg & 3) * 8;       // col within plane
        if (grow < NN)
            *(bf16x8*)(Vp + (long)plane * PAD_N * 32 + (long)grow * 32 + pc) =
                *(const bf16x8*)&As[row * 132 + seg * 8];
    }
}

// Kernel C: softmax alphas -> fp16  alpha[node][head][edge].
// 8 nodes per block; 32 lanes per node.
__global__ __launch_bounds__(256) void alpha_kernel(const int* __restrict__ src,
        const float* __restrict__ sq, const float* __restrict__ sk,
        ushort* __restrict__ alpha) {
    const int t = threadIdx.x;
    const int e = t & 31;
    const int n = blockIdx.x * 8 + (t >> 5);    // grid*8 == NN exactly
    const int s = src[(long)n * KE + e];
    float4 sk4 = *(const float4*)(sk + (long)s * 4);
    float4 sq4 = *(const float4*)(sq + (long)n * 4);
    float ev[4] = { sq4.x + sk4.x, sq4.y + sk4.y, sq4.z + sk4.z, sq4.w + sk4.w };
#pragma unroll
    for (int h = 0; h < 4; ++h) ev[h] = ev[h] > 0.f ? ev[h] : 0.2f * ev[h];
    float m[4] = { ev[0], ev[1], ev[2], ev[3] };
#pragma unroll
    for (int off = 16; off > 0; off >>= 1) {
#pragma unroll
        for (int h = 0; h < 4; ++h) m[h] = fmaxf(m[h], __shfl_xor(m[h], off));
    }
    float ex[4], sum[4];
#pragma unroll
    for (int h = 0; h < 4; ++h) { ex[h] = __expf(ev[h] - m[h]); sum[h] = ex[h]; }
#pragma unroll
    for (int off = 16; off > 0; off >>= 1) {
#pragma unroll
        for (int h = 0; h < 4; ++h) sum[h] += __shfl_xor(sum[h], off);
    }
#pragma unroll
    for (int h = 0; h < 4; ++h)
        alpha[(long)n * 128 + h * 32 + e] = f2h(ex[h] / (sum[h] + 1e-8f));
}

// Kernel D: column-sliced gather.  slice == head; block -> slice via
// (blockIdx%8)>>1 so each XCD pair touches only one 3.2 MB V plane
// (L2-resident).  Writes z (pre-LN) into d_out fp32.
__global__ __launch_bounds__(256) void gather_kernel(const int* __restrict__ src,
        const ushort* __restrict__ alpha, const ushort* __restrict__ Vp,
        float* __restrict__ z) {
    __shared__ int   s_src[32 * 33];
    __shared__ float s_al [32 * 33];
    const int b = blockIdx.x;
    const int head = (b & 7) >> 1;
    const int chunk = (b >> 3) * 2 + (b & 1);   // 0..1563
    const int nbase = chunk * 32;
    const int t = threadIdx.x;

#pragma unroll
    for (int i = 0; i < 4; ++i) {
        const int idx = i * 256 + t;
        const int n = idx >> 5, e = idx & 31;
        const int nn = nbase + n;
        s_src[n * 33 + e] = (nn < NN) ? src[(long)nn * KE + e] : 0;
        const ushort a = (nn < NN) ? alpha[(long)nn * 128 + head * 32 + e] : 0;
        s_al[n * 33 + e] = h2f(a);
    }
    __syncthreads();

    const int slot = t >> 3;        // node slot 0..31
    const int l = t & 7;            // 4 cols per lane
    const int node = nbase + slot;
    const ushort* plane = Vp + (long)head * PAD_N * 32;
    float z0 = 0.f, z1 = 0.f, z2 = 0.f, z3 = 0.f;
#pragma unroll 8
    for (int e = 0; e < 32; ++e) {
        const int sidx = s_src[slot * 33 + e];
        const float a = s_al[slot * 33 + e];
        uint2 p = *(const uint2*)(plane + (long)sidx * 32 + l * 4);
        union { unsigned u; float f; } e0, o0, e1, o1;
        e0.u = p.x << 16; o0.u = p.x & 0xffff0000u;
        e1.u = p.y << 16; o1.u = p.y & 0xffff0000u;
        z0 += a * e0.f; z1 += a * o0.f; z2 += a * e1.f; z3 += a * o1.f;
    }
    if (node < NN)
        *(float4*)(z + (long)node * 128 + head * 32 + l * 4) =
            make_float4(z0, z1, z2, z3);
}

// Kernel E: in-place ELU + LayerNorm on d_out.  One wave per node.
__global__ __launch_bounds__(256) void lnorm_kernel(float* __restrict__ z,
        const float* __restrict__ gamma, const float* __restrict__ beta) {
    const int w = threadIdx.x >> 6;
    const int lane = threadIdx.x & 63;
    const int n = blockIdx.x * 4 + w;           // grid*4 == NN exactly
    const int c0 = lane * 2;
    float2 zv = *(const float2*)(z + (long)n * 128 + c0);
    float zx = zv.x, zy = zv.y;
    zx = zx > 0.f ? zx : __expf(zx) - 1.f;
    zy = zy > 0.f ? zy : __expf(zy) - 1.f;
    float s1 = zx + zy;
    float s2 = zx * zx + zy * zy;
#pragma unroll
    for (int off = 32; off > 0; off >>= 1) {
        s1 += __shfl_xor(s1, off);
        s2 += __shfl_xor(s2, off);
    }
    const float mu = s1 * (1.f / 128.f);
    const float var = s2 * (1.f / 128.f) - mu * mu;
    const float rstd = rsqrtf(var + 1e-5f);
    float2 g = *(const float2*)(gamma + c0);
    float2 b = *(const float2*)(beta + c0);
    float2 o;
    o.x = (zx - mu) * rstd * g.x + b.x;
    o.y = (zy - mu) * rstd * g.y + b.y;
    *(float2*)(z + (long)n * 128 + c0) = o;
}

extern "C" void kernel_launch(void* const* d_in, const int* in_sizes, int n_in,
                              void* d_out, int out_size, void* d_ws, size_t ws_size,
                              hipStream_t stream) {
    const float* x     = (const float*)d_in[0];
    const float* emb   = (const float*)d_in[1];
    const int*   edge  = (const int*)d_in[2];
    const float* Wq    = (const float*)d_in[3];
    const float* Wk    = (const float*)d_in[4];
    const float* Wv    = (const float*)d_in[5];
    const float* av    = (const float*)d_in[6];
    const float* gamma = (const float*)d_in[7];
    const float* beta  = (const float*)d_in[8];
    float* out = (float*)d_out;

    char* ws = (char*)d_ws;
    ushort* Ub    = (ushort*)(ws + 0);            //    4 KB
    ushort* Bt    = (ushort*)(ws + 4096);         //   64 KB
    float*  sq    = (float*)(ws + 69632);         //  800 KB
    float*  sk    = (float*)(ws + 869632);        //  800 KB
    ushort* alpha = (ushort*)(ws + 1669632);      // 12.8 MB
    ushort* Vp    = (ushort*)(ws + 14469632);     // 12.8 MB (4 planes)
    // total ~27.3 MB

    prep_kernel<<<130, 256, 0, stream>>>(Wq, Wk, av, Wv, Ub, Bt);
    vproj_mfma<<<(NN + 63) / 64, 256, 0, stream>>>(x, emb, Bt, Ub, sq, sk, Vp);
    alpha_kernel<<<NN / 8, 256, 0, stream>>>(edge, sq, sk, alpha);
    gather_kernel<<<782 * 8, 256, 0, stream>>>(edge, alpha, Vp, out);
    lnorm_kernel<<<NN / 4, 256, 0, stream>>>(out, gamma, beta);
}

// Round 6
// 195.736 us; speedup vs baseline: 1.0021x; 1.0021x over previous
//
#include <hip/hip_runtime.h>

#define NN 50000
#define KE 32
#define PAD_N 50048     // padded rows per V plane

using f32x4  = __attribute__((ext_vector_type(4))) float;
using bf16x8 = __attribute__((ext_vector_type(8))) short;

__device__ __forceinline__ ushort f2bf(float f) {
    union { float f; unsigned u; } c; c.f = f;
    unsigned u = c.u;
    u += 0x7fffu + ((u >> 16) & 1u);        // round-to-nearest-even
    return (ushort)(u >> 16);
}

// Kernel A (blocks 0-1): fold attn_vec through W_q/W_k into bf16 Ub[16][128]
// (cols 0-3 = u_h, 4-7 = v_h, rows 8-15 zeroed for MFMA B-operand).
// Blocks 2..129: cast W_v into Bt[n][k] = bf16(W_v[k][n]).
__global__ __launch_bounds__(256) void prep_kernel(const float* __restrict__ Wq,
        const float* __restrict__ Wk, const float* __restrict__ av,
        const float* __restrict__ Wv, ushort* __restrict__ Ub,
        ushort* __restrict__ Bt) {
    const int g = blockIdx.x * 256 + threadIdx.x;
    if (blockIdx.x < 2) {
        const int h = g >> 7, i = g & 127;
        float su = 0.f, sv = 0.f;
#pragma unroll
        for (int d = 0; d < 32; ++d) {
            su += Wq[i * 128 + h * 32 + d] * av[h * 64 + d];
            sv += Wk[i * 128 + h * 32 + d] * av[h * 64 + 32 + d];
        }
        Ub[h * 128 + i] = f2bf(su);
        Ub[(4 + h) * 128 + i] = f2bf(sv);
        Ub[1024 + g * 2] = 0;               // zero rows 8..15
        Ub[1024 + g * 2 + 1] = 0;
    } else {
        const int idx = g - 512;            // coalesced read of Wv
        const int k = idx >> 7, n = idx & 127;
        Bt[n * 256 + k] = f2bf(Wv[idx]);
    }
}

// Kernel B: V = concat(x, emb) @ W_v via bf16 MFMA + fused sq/sk scores.
// Scores stored transposed (sqT/skT[head][node]) so the gather's per-XCD
// working set stays L2-resident. V written as 4 column planes (bf16).
__global__ __launch_bounds__(256) void vproj_mfma(const float* __restrict__ x,
        const float* __restrict__ emb, const ushort* __restrict__ Bt,
        const ushort* __restrict__ Ub, float* __restrict__ sqT,
        float* __restrict__ skT, ushort* __restrict__ Vp) {
    __shared__ short As[64 * 264];
    const int t = threadIdx.x;
    const int rbase = blockIdx.x * 64;
    const int wv = t >> 6;
    const int lane = t & 63;
    const int lo = lane & 15;
    const int quad = lane >> 4;
    const int c0 = wv * 32;

    // ---- stage A: 64 rows x 256 k, fp32 -> bf16 ----
#pragma unroll
    for (int it = 0; it < 16; ++it) {
        const int li = it * 256 + t;
        const int row = li >> 6;
        const int c4 = li & 63;
        int rg = rbase + row; if (rg >= NN) rg = NN - 1;
        const float* sp = (c4 < 32) ? (x + (long)rg * 128 + c4 * 4)
                                    : (emb + (long)rg * 128 + (c4 - 32) * 4);
        float4 a = *(const float4*)sp;
        ushort4 b = make_ushort4(f2bf(a.x), f2bf(a.y), f2bf(a.z), f2bf(a.w));
        *(ushort4*)&As[row * 264 + c4 * 4] = b;
    }
    // ---- preload all Bt fragments (latency overlaps the barrier) ----
    bf16x8 bt0[8], bt1[8];
#pragma unroll
    for (int ks = 0; ks < 8; ++ks) {
        const int kb = ks * 32 + quad * 8;
        bt0[ks] = *(const bf16x8*)(Bt + (c0 + lo) * 256 + kb);
        bt1[ks] = *(const bf16x8*)(Bt + (c0 + 16 + lo) * 256 + kb);
    }
    __syncthreads();

    f32x4 acc[4][2] = {};
#pragma unroll
    for (int ks = 0; ks < 8; ++ks) {
        const int kb = ks * 32 + quad * 8;
#pragma unroll
        for (int rt = 0; rt < 4; ++rt) {
            bf16x8 af = *(const bf16x8*)&As[(rt * 16 + lo) * 264 + kb];
            acc[rt][0] = __builtin_amdgcn_mfma_f32_16x16x32_bf16(af, bt0[ks], acc[rt][0], 0, 0, 0);
            acc[rt][1] = __builtin_amdgcn_mfma_f32_16x16x32_bf16(af, bt1[ks], acc[rt][1], 0, 0, 0);
        }
    }

    // ---- scores: wave wv handles rows wv*16..+15 (emb half of As) ----
    f32x4 sacc = {};
#pragma unroll
    for (int ks = 0; ks < 4; ++ks) {
        const int kk = ks * 32 + quad * 8;
        bf16x8 saf = *(const bf16x8*)&As[(wv * 16 + lo) * 264 + 128 + kk];
        bf16x8 sbf = *(const bf16x8*)(Ub + lo * 128 + kk);
        sacc = __builtin_amdgcn_mfma_f32_16x16x32_bf16(saf, sbf, sacc, 0, 0, 0);
    }
    if (lo < 8) {
#pragma unroll
        for (int r = 0; r < 4; ++r) {
            const int row = rbase + wv * 16 + quad * 4 + r;
            if (row < NN) {
                if (lo < 4) sqT[(long)lo * NN + row] = sacc[r];
                else        skT[(long)(lo - 4) * NN + row] = sacc[r];
            }
        }
    }

    // ---- epilogue: regs -> LDS (stride 132) -> sliced planes ----
    __syncthreads();
#pragma unroll
    for (int rt = 0; rt < 4; ++rt)
#pragma unroll
        for (int ct = 0; ct < 2; ++ct)
#pragma unroll
            for (int r = 0; r < 4; ++r)
                As[(rt * 16 + quad * 4 + r) * 132 + c0 + ct * 16 + lo] =
                    (short)f2bf(acc[rt][ct][r]);
    __syncthreads();
#pragma unroll
    for (int i = 0; i < 4; ++i) {
        const int idx = i * 256 + t;
        const int row = idx >> 4;
        const int seg = idx & 15;           // cols seg*8 .. seg*8+7
        const int grow = rbase + row;
        const int plane = seg >> 2;         // head
        const int pc = (seg & 3) * 8;       // col within plane
        if (grow < NN)
            *(bf16x8*)(Vp + (long)plane * PAD_N * 32 + (long)grow * 32 + pc) =
                *(const bf16x8*)&As[row * 132 + seg * 8];
    }
}

// Kernel C: head-sliced gather with INLINE softmax.  Block = 64 nodes x 1
// head; head pinned to an XCD pair via (blockIdx%8)>>1 so each XCD touches
// one 3.2 MB V plane + 0.4 MB scores (L2-resident).  Phase 1 computes alpha
// for the 64 nodes (fp32, in LDS); phase 2 gathers V with 16 B/lane loads,
// unroll 16 for MLP.  Writes pre-LN z (fp32) into d_out.
__global__ __launch_bounds__(256) void gather_kernel(const int* __restrict__ src,
        const float* __restrict__ sqT, const float* __restrict__ skT,
        const ushort* __restrict__ Vp, float* __restrict__ z) {
    __shared__ int   s_src[64 * 33];
    __shared__ float s_al [64 * 33];
    const int b = blockIdx.x;
    const int head = (b & 7) >> 1;
    const int chunk = (b >> 3) * 2 + (b & 1);   // 0..781
    const int nbase = chunk * 64;
    const int t = threadIdx.x;
    const int e = t & 31;

    // ---- phase 1: inline softmax over each node's 32 edges ----
    const float* sqh = sqT + (long)head * NN;
    const float* skh = skT + (long)head * NN;
#pragma unroll
    for (int p = 0; p < 8; ++p) {
        const int slot = p * 8 + (t >> 5);
        const int n = nbase + slot;
        const bool valid = n < NN;
        const int s = valid ? src[(long)n * KE + e] : 0;
        float ev = valid ? (sqh[n] + skh[s]) : 0.f;
        ev = ev > 0.f ? ev : 0.2f * ev;
        float m = ev;
#pragma unroll
        for (int off = 16; off > 0; off >>= 1)
            m = fmaxf(m, __shfl_xor(m, off));
        const float ex = __expf(ev - m);
        float sum = ex;
#pragma unroll
        for (int off = 16; off > 0; off >>= 1)
            sum += __shfl_xor(sum, off);
        s_src[slot * 33 + e] = s;
        s_al[slot * 33 + e] = ex / (sum + 1e-8f);
    }
    __syncthreads();

    // ---- phase 2: weighted gather, 4 lanes x 16 B per edge-row ----
    const int slot = t >> 2;        // 0..63
    const int l = t & 3;            // cols l*8 .. l*8+7 within the plane
    const ushort* plane = Vp + (long)head * PAD_N * 32 + l * 8;
    float z0 = 0.f, z1 = 0.f, z2 = 0.f, z3 = 0.f;
    float z4 = 0.f, z5 = 0.f, z6 = 0.f, z7 = 0.f;
#pragma unroll 16
    for (int ee = 0; ee < 32; ++ee) {
        const int sidx = s_src[slot * 33 + ee];
        const float a = s_al[slot * 33 + ee];
        uint4 p = *(const uint4*)(plane + (long)sidx * 32);
        union { unsigned u; float f; } c0e, c0o, c1e, c1o, c2e, c2o, c3e, c3o;
        c0e.u = p.x << 16; c0o.u = p.x & 0xffff0000u;
        c1e.u = p.y << 16; c1o.u = p.y & 0xffff0000u;
        c2e.u = p.z << 16; c2o.u = p.z & 0xffff0000u;
        c3e.u = p.w << 16; c3o.u = p.w & 0xffff0000u;
        z0 += a * c0e.f; z1 += a * c0o.f;
        z2 += a * c1e.f; z3 += a * c1o.f;
        z4 += a * c2e.f; z5 += a * c2o.f;
        z6 += a * c3e.f; z7 += a * c3o.f;
    }
    const int node = nbase + slot;
    if (node < NN) {
        float* zp = z + (long)node * 128 + head * 32 + l * 8;
        *(float4*)(zp)     = make_float4(z0, z1, z2, z3);
        *(float4*)(zp + 4) = make_float4(z4, z5, z6, z7);
    }
}

// Kernel D: in-place ELU + LayerNorm on d_out.  One wave per node.
__global__ __launch_bounds__(256) void lnorm_kernel(float* __restrict__ z,
        const float* __restrict__ gamma, const float* __restrict__ beta) {
    const int w = threadIdx.x >> 6;
    const int lane = threadIdx.x & 63;
    const int n = blockIdx.x * 4 + w;           // grid*4 == NN exactly
    const int c0 = lane * 2;
    float2 zv = *(const float2*)(z + (long)n * 128 + c0);
    float zx = zv.x, zy = zv.y;
    zx = zx > 0.f ? zx : __expf(zx) - 1.f;
    zy = zy > 0.f ? zy : __expf(zy) - 1.f;
    float s1 = zx + zy;
    float s2 = zx * zx + zy * zy;
#pragma unroll
    for (int off = 32; off > 0; off >>= 1) {
        s1 += __shfl_xor(s1, off);
        s2 += __shfl_xor(s2, off);
    }
    const float mu = s1 * (1.f / 128.f);
    const float var = s2 * (1.f / 128.f) - mu * mu;
    const float rstd = rsqrtf(var + 1e-5f);
    float2 g = *(const float2*)(gamma + c0);
    float2 b = *(const float2*)(beta + c0);
    float2 o;
    o.x = (zx - mu) * rstd * g.x + b.x;
    o.y = (zy - mu) * rstd * g.y + b.y;
    *(float2*)(z + (long)n * 128 + c0) = o;
}

extern "C" void kernel_launch(void* const* d_in, const int* in_sizes, int n_in,
                              void* d_out, int out_size, void* d_ws, size_t ws_size,
                              hipStream_t stream) {
    const float* x     = (const float*)d_in[0];
    const float* emb   = (const float*)d_in[1];
    const int*   edge  = (const int*)d_in[2];
    const float* Wq    = (const float*)d_in[3];
    const float* Wk    = (const float*)d_in[4];
    const float* Wv    = (const float*)d_in[5];
    const float* av    = (const float*)d_in[6];
    const float* gamma = (const float*)d_in[7];
    const float* beta  = (const float*)d_in[8];
    float* out = (float*)d_out;

    char* ws = (char*)d_ws;
    ushort* Ub  = (ushort*)(ws + 0);            //    4 KB
    ushort* Bt  = (ushort*)(ws + 4096);         //   64 KB
    float*  sqT = (float*)(ws + 69632);         //  800 KB  [head][node] (4*NN*4B)
    float*  skT = (float*)(ws + 869632);        //  800 KB  [head][node]
    ushort* Vp  = (ushort*)(ws + 1669632);      // 12.8 MB (4 planes)

    prep_kernel<<<130, 256, 0, stream>>>(Wq, Wk, av, Wv, Ub, Bt);
    vproj_mfma<<<(NN + 63) / 64, 256, 0, stream>>>(x, emb, Bt, Ub, sqT, skT, Vp);
    gather_kernel<<<782 * 4, 256, 0, stream>>>(edge, sqT, skT, Vp, out);
    lnorm_kernel<<<NN / 4, 256, 0, stream>>>(out, gamma, beta);
}